// Round 6
// baseline (1095.621 us; speedup 1.0000x reference)
//
#include <hip/hip_runtime.h>
#include <math.h>

#define B_ 2
#define S_ 2048
#define D_ 1024
#define H_ 16
#define DK_ 64
#define EPS_ 1e-5f

typedef __bf16 bf16_t;
typedef __bf16 bf16x4 __attribute__((ext_vector_type(4)));
typedef __bf16 bf16x8 __attribute__((ext_vector_type(8)));
typedef float f32x4 __attribute__((ext_vector_type(4)));
typedef unsigned long long u64;

// ---------------------------------------------------------------------------
// Pack int32 mask [B,S,S] -> bitmask [B,S,S/64] (1 bit per entry).
// ---------------------------------------------------------------------------
__global__ __launch_bounds__(256) void mask_pack(const int* __restrict__ mask,
                                                 u64* __restrict__ bits)
{
    size_t i = (size_t)blockIdx.x * 256 + threadIdx.x;
    int m = mask[i];
    u64 b = __ballot(m != 0);
    if ((threadIdx.x & 63) == 0) bits[i >> 6] = b;
}

// ---------------------------------------------------------------------------
// Projection: Y = X @ W^T + b  (X:[4096,1024] fp32, W:[1024,1024] fp32)
// Output bf16, head-split. vmode==0 -> [B,H,S,DK]; vmode==1 -> [B,H,DK,S].
// ---------------------------------------------------------------------------
__global__ __launch_bounds__(256) void proj_mfma(const float* __restrict__ X,
        const float* __restrict__ W, const float* __restrict__ bias,
        bf16_t* __restrict__ out, int vmode)
{
    __shared__ bf16_t As[64][72];
    __shared__ bf16_t Bs[64][72];
    int tid = threadIdx.x;
    int w = tid >> 6, l = tid & 63;
    int m0 = blockIdx.y * 64, n0 = blockIdx.x * 64;
    f32x4 acc[4] = {};
    for (int k0 = 0; k0 < D_; k0 += 64) {
#pragma unroll
        for (int i = 0; i < 4; ++i) {
            int u = tid + i * 256;              // 1024 float4 units
            int r = u >> 4, c4 = (u & 15) * 4;
            float4 xv = *reinterpret_cast<const float4*>(&X[(size_t)(m0 + r) * D_ + k0 + c4]);
            bf16x4 bx = { (bf16_t)xv.x, (bf16_t)xv.y, (bf16_t)xv.z, (bf16_t)xv.w };
            *reinterpret_cast<bf16x4*>(&As[r][c4]) = bx;
            float4 wv = *reinterpret_cast<const float4*>(&W[(size_t)(n0 + r) * D_ + k0 + c4]);
            bf16x4 bw = { (bf16_t)wv.x, (bf16_t)wv.y, (bf16_t)wv.z, (bf16_t)wv.w };
            *reinterpret_cast<bf16x4*>(&Bs[r][c4]) = bw;
        }
        __syncthreads();
#pragma unroll
        for (int kk = 0; kk < 64; kk += 32) {
            bf16x8 a = *reinterpret_cast<const bf16x8*>(&As[w * 16 + (l & 15)][kk + (l >> 4) * 8]);
#pragma unroll
            for (int t = 0; t < 4; ++t) {
                bf16x8 b = *reinterpret_cast<const bf16x8*>(&Bs[t * 16 + (l & 15)][kk + (l >> 4) * 8]);
                acc[t] = __builtin_amdgcn_mfma_f32_16x16x32_bf16(a, b, acc[t], 0, 0, 0);
            }
        }
        __syncthreads();
    }
    int h = n0 >> 6;  // each 64-wide n-tile is exactly one head
#pragma unroll
    for (int t = 0; t < 4; ++t) {
#pragma unroll
        for (int r = 0; r < 4; ++r) {
            int m = m0 + w * 16 + (l >> 4) * 4 + r;
            int n = n0 + t * 16 + (l & 15);
            float val = acc[t][r] + bias[n];
            int b = m >> 11, s = m & (S_ - 1);
            int dk = n & 63;
            size_t idx;
            if (vmode == 0) idx = (((size_t)b * H_ + h) * S_ + s) * DK_ + dk;
            else            idx = (((size_t)b * H_ + h) * DK_ + dk) * S_ + s;
            out[idx] = (bf16_t)val;
        }
    }
}

// ---------------------------------------------------------------------------
// Fused attention, no-max softmax, key-split across wave pairs.
// 8 waves/block: wave (sub, sub+4) share q-subtile sub (16 rows); wave's
// "half" bit selects keys [0,1024) or [1024,2048). Pass 1: partial row-sums
// of exp -> LDS pair-reduce. Pass 2: recompute QK^T, p=exp*inv_l (mask via
// bit-select), plain f32x4 store, stage bf16 P in wave-private LDS, PV MFMA.
// oacc pair-reduced via LDS at the end. 2 barriers/block total.
// Grid 1D 1024, XCD-swizzled: xcd = id&7 owns 4 consecutive bh.
// ---------------------------------------------------------------------------
__global__ __launch_bounds__(512, 8) void fused_attn(
        const bf16_t* __restrict__ qh,   // [B,H,S,DK]
        const bf16_t* __restrict__ kh,   // [B,H,S,DK]
        const bf16_t* __restrict__ vt,   // [B,H,DK,S]
        const u64*    __restrict__ bits, // [B,S,S/64]
        float* __restrict__ attn,        // [B,H,S,S]
        bf16_t* __restrict__ ctx)        // [B,S,D] bf16
{
    __shared__ bf16_t Ps[8][16][72];     // wave-private P staging
    __shared__ float Lred[8][16];        // l_r pair-reduce
    __shared__ float Ored[4][16][64];    // oacc pair-reduce

    const int tid = threadIdx.x;
    const int w = tid >> 6, l = tid & 63;
    const int sub = w & 3, half = w >> 2;
    const int c = l & 15, g = l >> 4;    // c: q within subtile; g: key group
    // XCD swizzle: 1024 blocks, 8 XCDs -> 128 blocks/XCD = 4 bh x 32 q-tiles
    const int id = blockIdx.x;
    const int xcd = id & 7, ixd = id >> 3;
    const int bh = xcd * 4 + (ixd >> 5);
    const int qt = ixd & 31;
    const int q0 = qt * 64 + sub * 16;
    const int b = bh >> 4, h = bh & 15;
    const int kbase = half * (S_ / 2);

    const bf16_t* Q = qh + ((size_t)bh * S_ + q0) * DK_;
    const bf16_t* K = kh + (size_t)bh * S_ * DK_;
    const bf16_t* V = vt + (size_t)bh * DK_ * S_;
    const u64* Mb = bits + ((size_t)b * S_ + q0 + c) * (S_ / 64);
    float* A = attn + ((size_t)bh * S_ + q0 + c) * S_;      // lane's q row

    // Q fragment (B-operand): row = q0+c, dk slice = g*8 (+32 for second half)
    bf16x8 qf0 = *reinterpret_cast<const bf16x8*>(&Q[c * DK_ + g * 8]);
    bf16x8 qf1 = *reinterpret_cast<const bf16x8*>(&Q[c * DK_ + 32 + g * 8]);

    // ---- pass 1: partial row sums of exp over own key half ----
    float l_r = 0.f;
    for (int k0 = kbase; k0 < kbase + S_ / 2; k0 += 64) {
        u64 word = Mb[k0 >> 6];
        f32x4 acc[4] = {};
#pragma unroll
        for (int tk = 0; tk < 4; ++tk) {
            const bf16_t* Kb = &K[(size_t)(k0 + tk * 16 + c) * DK_ + g * 8];
            bf16x8 a0 = *reinterpret_cast<const bf16x8*>(Kb);
            bf16x8 a1 = *reinterpret_cast<const bf16x8*>(Kb + 32);
            acc[tk] = __builtin_amdgcn_mfma_f32_16x16x32_bf16(a0, qf0, acc[tk], 0, 0, 0);
            acc[tk] = __builtin_amdgcn_mfma_f32_16x16x32_bf16(a1, qf1, acc[tk], 0, 0, 0);
        }
        float ps = 0.f;
#pragma unroll
        for (int tk = 0; tk < 4; ++tk) {
#pragma unroll
            for (int r = 0; r < 4; ++r) {
                float e = __expf(acc[tk][r] * 0.125f);
                e = ((word >> (tk * 16 + g * 4 + r)) & 1) ? e : 0.f;
                ps += e;
            }
        }
        l_r += ps;
    }
    l_r += __shfl_xor(l_r, 16);
    l_r += __shfl_xor(l_r, 32);
    if (l < 16) Lred[w][l] = l_r;
    __syncthreads();
    const float inv_l = 1.0f / (Lred[sub][c] + Lred[sub + 4][c]);

    // ---- pass 2: recompute, normalize, emit P, PV over own key half ----
    f32x4 oacc[4] = {};
    for (int k0 = kbase; k0 < kbase + S_ / 2; k0 += 64) {
        u64 word = Mb[k0 >> 6];
        f32x4 acc[4] = {};
#pragma unroll
        for (int tk = 0; tk < 4; ++tk) {
            const bf16_t* Kb = &K[(size_t)(k0 + tk * 16 + c) * DK_ + g * 8];
            bf16x8 a0 = *reinterpret_cast<const bf16x8*>(Kb);
            bf16x8 a1 = *reinterpret_cast<const bf16x8*>(Kb + 32);
            acc[tk] = __builtin_amdgcn_mfma_f32_16x16x32_bf16(a0, qf0, acc[tk], 0, 0, 0);
            acc[tk] = __builtin_amdgcn_mfma_f32_16x16x32_bf16(a1, qf1, acc[tk], 0, 0, 0);
        }
#pragma unroll
        for (int tk = 0; tk < 4; ++tk) {
            f32x4 pv;
            bf16x4 pb;
#pragma unroll
            for (int r = 0; r < 4; ++r) {
                float p = __expf(acc[tk][r] * 0.125f) * inv_l;
                p = ((word >> (tk * 16 + g * 4 + r)) & 1) ? p : 0.f;
                pv[r] = p;
                pb[r] = (bf16_t)p;
            }
            *reinterpret_cast<f32x4*>(&A[k0 + tk * 16 + g * 4]) = pv;
            *reinterpret_cast<bf16x4*>(&Ps[w][c][tk * 16 + g * 4]) = pb;
        }
        // wave-private LDS write -> read; no barrier, just drain DS queue
        asm volatile("s_waitcnt lgkmcnt(0)" ::: "memory");
        bf16x8 pa0 = *reinterpret_cast<const bf16x8*>(&Ps[w][c][g * 8]);
        bf16x8 pa1 = *reinterpret_cast<const bf16x8*>(&Ps[w][c][32 + g * 8]);
#pragma unroll
        for (int tk = 0; tk < 4; ++tk) {
            const bf16_t* Vb = &V[(size_t)(tk * 16 + c) * S_ + k0 + g * 8];
            bf16x8 b0 = *reinterpret_cast<const bf16x8*>(Vb);
            bf16x8 b1 = *reinterpret_cast<const bf16x8*>(Vb + 32);
            oacc[tk] = __builtin_amdgcn_mfma_f32_16x16x32_bf16(pa0, b0, oacc[tk], 0, 0, 0);
            oacc[tk] = __builtin_amdgcn_mfma_f32_16x16x32_bf16(pa1, b1, oacc[tk], 0, 0, 0);
        }
    }

    // ---- pair-reduce oacc across key halves, then ctx write by half 0 ----
    if (half == 1) {
#pragma unroll
        for (int j = 0; j < 16; ++j) Ored[sub][j][l] = oacc[j >> 2][j & 3];
    }
    __syncthreads();
    if (half == 0) {
#pragma unroll
        for (int j = 0; j < 16; ++j) oacc[j >> 2][j & 3] += Ored[sub][j][l];
        // ctx write: row = q0 + g*4 + r, col = h*64 + tk*16 + c
#pragma unroll
        for (int tk = 0; tk < 4; ++tk) {
#pragma unroll
            for (int r = 0; r < 4; ++r) {
                int q = q0 + g * 4 + r;
                ctx[((size_t)b * S_ + q) * D_ + h * DK_ + tk * 16 + c] = (bf16_t)oacc[tk][r];
            }
        }
    }
}

// ---------------------------------------------------------------------------
// Output projection + bias + residual -> x (fp32). A = ctx bf16, B = Wo fp32.
// ---------------------------------------------------------------------------
__global__ __launch_bounds__(256) void oproj_mfma(const bf16_t* __restrict__ ctx,
        const float* __restrict__ Wo, const float* __restrict__ bo,
        const float* __restrict__ resid, float* __restrict__ x)
{
    __shared__ bf16_t As[64][72];
    __shared__ bf16_t Bs[64][72];
    int tid = threadIdx.x;
    int w = tid >> 6, l = tid & 63;
    int m0 = blockIdx.y * 64, n0 = blockIdx.x * 64;
    f32x4 acc[4] = {};
    for (int k0 = 0; k0 < D_; k0 += 64) {
#pragma unroll
        for (int i = 0; i < 2; ++i) {
            int u = tid + i * 256;
            int r = u >> 3, c8 = (u & 7) * 8;
            *reinterpret_cast<bf16x8*>(&As[r][c8]) =
                *reinterpret_cast<const bf16x8*>(&ctx[(size_t)(m0 + r) * D_ + k0 + c8]);
        }
#pragma unroll
        for (int i = 0; i < 4; ++i) {
            int u = tid + i * 256;
            int r = u >> 4, c4 = (u & 15) * 4;
            float4 wv = *reinterpret_cast<const float4*>(&Wo[(size_t)(n0 + r) * D_ + k0 + c4]);
            bf16x4 bw = { (bf16_t)wv.x, (bf16_t)wv.y, (bf16_t)wv.z, (bf16_t)wv.w };
            *reinterpret_cast<bf16x4*>(&Bs[r][c4]) = bw;
        }
        __syncthreads();
#pragma unroll
        for (int kk = 0; kk < 64; kk += 32) {
            bf16x8 a = *reinterpret_cast<const bf16x8*>(&As[w * 16 + (l & 15)][kk + (l >> 4) * 8]);
#pragma unroll
            for (int t = 0; t < 4; ++t) {
                bf16x8 b = *reinterpret_cast<const bf16x8*>(&Bs[t * 16 + (l & 15)][kk + (l >> 4) * 8]);
                acc[t] = __builtin_amdgcn_mfma_f32_16x16x32_bf16(a, b, acc[t], 0, 0, 0);
            }
        }
        __syncthreads();
    }
#pragma unroll
    for (int t = 0; t < 4; ++t) {
#pragma unroll
        for (int r = 0; r < 4; ++r) {
            int m = m0 + w * 16 + (l >> 4) * 4 + r;
            int n = n0 + t * 16 + (l & 15);
            x[(size_t)m * D_ + n] = acc[t][r] + bo[n] + resid[(size_t)m * D_ + n];
        }
    }
}

// ---------------------------------------------------------------------------
// LayerNorm over last dim (1024), 4096 rows
// ---------------------------------------------------------------------------
__global__ void ln_kernel(const float* __restrict__ x, const float* __restrict__ gamma,
                          const float* __restrict__ beta, float* __restrict__ out)
{
    int row = blockIdx.x;
    const float* xr = x + (size_t)row * D_;
    int tid = threadIdx.x;
    float v[4];
    float s = 0.f;
#pragma unroll
    for (int i = 0; i < 4; ++i) {
        v[i] = xr[tid + i * 256];
        s += v[i];
    }
#pragma unroll
    for (int off = 32; off > 0; off >>= 1) s += __shfl_xor(s, off);
    __shared__ float red[4];
    int wid = tid >> 6, lane = tid & 63;
    if (lane == 0) red[wid] = s;
    __syncthreads();
    float mu = (red[0] + red[1] + red[2] + red[3]) * (1.0f / D_);
    float vs = 0.f;
#pragma unroll
    for (int i = 0; i < 4; ++i) {
        float d = v[i] - mu;
        vs += d * d;
    }
#pragma unroll
    for (int off = 32; off > 0; off >>= 1) vs += __shfl_xor(vs, off);
    __syncthreads();
    __shared__ float red2[4];
    if (lane == 0) red2[wid] = vs;
    __syncthreads();
    float var = (red2[0] + red2[1] + red2[2] + red2[3]) * (1.0f / D_);
    float rs = rsqrtf(var + EPS_);
#pragma unroll
    for (int i = 0; i < 4; ++i) {
        int c = tid + i * 256;
        out[(size_t)row * D_ + c] = (v[i] - mu) * rs * gamma[c] + beta[c];
    }
}

extern "C" void kernel_launch(void* const* d_in, const int* in_sizes, int n_in,
                              void* d_out, int out_size, void* d_ws, size_t ws_size,
                              hipStream_t stream) {
    const float* q    = (const float*)d_in[0];
    const float* k    = (const float*)d_in[1];
    const float* v    = (const float*)d_in[2];
    const int*   mask = (const int*)d_in[3];
    const float* Wq   = (const float*)d_in[4];
    const float* bq   = (const float*)d_in[5];
    const float* Wk   = (const float*)d_in[6];
    const float* bk   = (const float*)d_in[7];
    const float* Wv   = (const float*)d_in[8];
    const float* bv   = (const float*)d_in[9];
    const float* Wo   = (const float*)d_in[10];
    const float* bo   = (const float*)d_in[11];
    const float* gamma= (const float*)d_in[12];
    const float* beta = (const float*)d_in[13];

    float* out  = (float*)d_out;                       // [B,S,D]
    float* attn = out + (size_t)B_ * S_ * D_;          // [B,H,S,S]

    uint8_t* ws = (uint8_t*)d_ws;
    bf16_t* qh   = (bf16_t*)(ws);                      // 8 MB  [B,H,S,DK]
    bf16_t* kh   = (bf16_t*)(ws + ((size_t)8  << 20)); // 8 MB  [B,H,S,DK]
    bf16_t* vt   = (bf16_t*)(ws + ((size_t)16 << 20)); // 8 MB  [B,H,DK,S]
    bf16_t* ctx  = (bf16_t*)(ws + ((size_t)24 << 20)); // 8 MB  [B,S,D]
    u64*    bits = (u64*)(ws + ((size_t)32 << 20));    // 1 MB  [B,S,S/64]
    float*  x    = (float*)(ws);                       // 16 MB, aliases qh+kh (dead by then)

    dim3 blk(256);
    // B_*S_*S_ = 8,388,608 ints; 256 threads/block -> 32768 blocks exactly.
    mask_pack<<<dim3((B_ * S_ * S_) / 256), blk, 0, stream>>>(mask, bits);

    dim3 gproj(D_ / 64, (B_ * S_) / 64);               // (16, 64)
    proj_mfma<<<gproj, blk, 0, stream>>>(q, Wq, bq, qh, 0);
    proj_mfma<<<gproj, blk, 0, stream>>>(k, Wk, bk, kh, 0);
    proj_mfma<<<gproj, blk, 0, stream>>>(v, Wv, bv, vt, 1);

    // 1024 blocks x 512 threads; XCD swizzle inside the kernel.
    fused_attn<<<dim3(1024), dim3(512), 0, stream>>>(qh, kh, vt, bits, attn, ctx);

    oproj_mfma<<<gproj, blk, 0, stream>>>(ctx, Wo, bo, q, x);
    ln_kernel<<<dim3(B_ * S_), blk, 0, stream>>>(x, gamma, beta, out);
}

// Round 7
// 691.456 us; speedup vs baseline: 1.5845x; 1.5845x over previous
//
#include <hip/hip_runtime.h>
#include <math.h>

#define B_ 2
#define S_ 2048
#define D_ 1024
#define H_ 16
#define DK_ 64
#define EPS_ 1e-5f

typedef __bf16 bf16_t;
typedef __bf16 bf16x4 __attribute__((ext_vector_type(4)));
typedef __bf16 bf16x8 __attribute__((ext_vector_type(8)));
typedef float f32x4 __attribute__((ext_vector_type(4)));
typedef unsigned long long u64;

// ---------------------------------------------------------------------------
// Pack int32 mask [B,S,S] -> bitmask [B,S,S/64] (1 bit per entry).
// ---------------------------------------------------------------------------
__global__ __launch_bounds__(256) void mask_pack(const int* __restrict__ mask,
                                                 u64* __restrict__ bits)
{
    size_t i = (size_t)blockIdx.x * 256 + threadIdx.x;
    int m = mask[i];
    u64 b = __ballot(m != 0);
    if ((threadIdx.x & 63) == 0) bits[i >> 6] = b;
}

// ---------------------------------------------------------------------------
// Projection: Y = X @ W^T + b  (X:[4096,1024] fp32, W:[1024,1024] fp32)
// Output bf16, head-split. vmode==0 -> [B,H,S,DK]; vmode==1 -> [B,H,DK,S].
// ---------------------------------------------------------------------------
__global__ __launch_bounds__(256) void proj_mfma(const float* __restrict__ X,
        const float* __restrict__ W, const float* __restrict__ bias,
        bf16_t* __restrict__ out, int vmode)
{
    __shared__ bf16_t As[64][72];
    __shared__ bf16_t Bs[64][72];
    int tid = threadIdx.x;
    int w = tid >> 6, l = tid & 63;
    int m0 = blockIdx.y * 64, n0 = blockIdx.x * 64;
    f32x4 acc[4] = {};
    for (int k0 = 0; k0 < D_; k0 += 64) {
#pragma unroll
        for (int i = 0; i < 4; ++i) {
            int u = tid + i * 256;              // 1024 float4 units
            int r = u >> 4, c4 = (u & 15) * 4;
            float4 xv = *reinterpret_cast<const float4*>(&X[(size_t)(m0 + r) * D_ + k0 + c4]);
            bf16x4 bx = { (bf16_t)xv.x, (bf16_t)xv.y, (bf16_t)xv.z, (bf16_t)xv.w };
            *reinterpret_cast<bf16x4*>(&As[r][c4]) = bx;
            float4 wv = *reinterpret_cast<const float4*>(&W[(size_t)(n0 + r) * D_ + k0 + c4]);
            bf16x4 bw = { (bf16_t)wv.x, (bf16_t)wv.y, (bf16_t)wv.z, (bf16_t)wv.w };
            *reinterpret_cast<bf16x4*>(&Bs[r][c4]) = bw;
        }
        __syncthreads();
#pragma unroll
        for (int kk = 0; kk < 64; kk += 32) {
            bf16x8 a = *reinterpret_cast<const bf16x8*>(&As[w * 16 + (l & 15)][kk + (l >> 4) * 8]);
#pragma unroll
            for (int t = 0; t < 4; ++t) {
                bf16x8 b = *reinterpret_cast<const bf16x8*>(&Bs[t * 16 + (l & 15)][kk + (l >> 4) * 8]);
                acc[t] = __builtin_amdgcn_mfma_f32_16x16x32_bf16(a, b, acc[t], 0, 0, 0);
            }
        }
        __syncthreads();
    }
    int h = n0 >> 6;  // each 64-wide n-tile is exactly one head
#pragma unroll
    for (int t = 0; t < 4; ++t) {
#pragma unroll
        for (int r = 0; r < 4; ++r) {
            int m = m0 + w * 16 + (l >> 4) * 4 + r;
            int n = n0 + t * 16 + (l & 15);
            float val = acc[t][r] + bias[n];
            int b = m >> 11, s = m & (S_ - 1);
            int dk = n & 63;
            size_t idx;
            if (vmode == 0) idx = (((size_t)b * H_ + h) * S_ + s) * DK_ + dk;
            else            idx = (((size_t)b * H_ + h) * DK_ + dk) * S_ + s;
            out[idx] = (bf16_t)val;
        }
    }
}

// ---------------------------------------------------------------------------
// Fused attention, no-max softmax, key-split across wave pairs.
// 8 waves/block: wave (sub, sub+4) share q-subtile sub (16 rows); wave's
// "half" bit selects keys [0,1024) or [1024,2048). Pass 1: partial row-sums
// of exp -> LDS pair-reduce. Pass 2: recompute QK^T, p=exp*inv_l (mask via
// bit-select), plain f32x4 store, stage bf16 P in wave-private LDS, PV MFMA.
// oacc pair-reduced via LDS at the end. 2 barriers/block total.
// Grid 1D 1024, XCD-swizzled: xcd = id&7 owns 4 consecutive bh.
// NOTE: no min-waves clamp in launch_bounds — (512,8) forced VGPR=32 and
// spilled (r6: FETCH 1.41 GB, 833us). Body needs ~60 VGPR; <=64 still
// allows 8 waves/SIMD.
// ---------------------------------------------------------------------------
__global__ __launch_bounds__(512) void fused_attn(
        const bf16_t* __restrict__ qh,   // [B,H,S,DK]
        const bf16_t* __restrict__ kh,   // [B,H,S,DK]
        const bf16_t* __restrict__ vt,   // [B,H,DK,S]
        const u64*    __restrict__ bits, // [B,S,S/64]
        float* __restrict__ attn,        // [B,H,S,S]
        bf16_t* __restrict__ ctx)        // [B,S,D] bf16
{
    __shared__ bf16_t Ps[8][16][72];     // wave-private P staging
    __shared__ float Lred[8][16];        // l_r pair-reduce
    __shared__ float Ored[4][16][64];    // oacc pair-reduce

    const int tid = threadIdx.x;
    const int w = tid >> 6, l = tid & 63;
    const int sub = w & 3, half = w >> 2;
    const int c = l & 15, g = l >> 4;    // c: q within subtile; g: key group
    // XCD swizzle: 1024 blocks, 8 XCDs -> 128 blocks/XCD = 4 bh x 32 q-tiles
    const int id = blockIdx.x;
    const int xcd = id & 7, ixd = id >> 3;
    const int bh = xcd * 4 + (ixd >> 5);
    const int qt = ixd & 31;
    const int q0 = qt * 64 + sub * 16;
    const int b = bh >> 4, h = bh & 15;
    const int kbase = half * (S_ / 2);

    const bf16_t* Q = qh + ((size_t)bh * S_ + q0) * DK_;
    const bf16_t* K = kh + (size_t)bh * S_ * DK_;
    const bf16_t* V = vt + (size_t)bh * DK_ * S_;
    const u64* Mb = bits + ((size_t)b * S_ + q0 + c) * (S_ / 64);
    float* A = attn + ((size_t)bh * S_ + q0 + c) * S_;      // lane's q row

    // Q fragment (B-operand): row = q0+c, dk slice = g*8 (+32 for second half)
    bf16x8 qf0 = *reinterpret_cast<const bf16x8*>(&Q[c * DK_ + g * 8]);
    bf16x8 qf1 = *reinterpret_cast<const bf16x8*>(&Q[c * DK_ + 32 + g * 8]);

    // ---- pass 1: partial row sums of exp over own key half ----
    float l_r = 0.f;
    for (int k0 = kbase; k0 < kbase + S_ / 2; k0 += 64) {
        u64 word = Mb[k0 >> 6];
        f32x4 acc[4] = {};
#pragma unroll
        for (int tk = 0; tk < 4; ++tk) {
            const bf16_t* Kb = &K[(size_t)(k0 + tk * 16 + c) * DK_ + g * 8];
            bf16x8 a0 = *reinterpret_cast<const bf16x8*>(Kb);
            bf16x8 a1 = *reinterpret_cast<const bf16x8*>(Kb + 32);
            acc[tk] = __builtin_amdgcn_mfma_f32_16x16x32_bf16(a0, qf0, acc[tk], 0, 0, 0);
            acc[tk] = __builtin_amdgcn_mfma_f32_16x16x32_bf16(a1, qf1, acc[tk], 0, 0, 0);
        }
        float ps = 0.f;
#pragma unroll
        for (int tk = 0; tk < 4; ++tk) {
#pragma unroll
            for (int r = 0; r < 4; ++r) {
                float e = __expf(acc[tk][r] * 0.125f);
                e = ((word >> (tk * 16 + g * 4 + r)) & 1) ? e : 0.f;
                ps += e;
            }
        }
        l_r += ps;
    }
    l_r += __shfl_xor(l_r, 16);
    l_r += __shfl_xor(l_r, 32);
    if (l < 16) Lred[w][l] = l_r;
    __syncthreads();
    const float inv_l = 1.0f / (Lred[sub][c] + Lred[sub + 4][c]);

    // ---- pass 2: recompute, normalize, emit P, PV over own key half ----
    f32x4 oacc[4] = {};
    for (int k0 = kbase; k0 < kbase + S_ / 2; k0 += 64) {
        u64 word = Mb[k0 >> 6];
        f32x4 acc[4] = {};
#pragma unroll
        for (int tk = 0; tk < 4; ++tk) {
            const bf16_t* Kb = &K[(size_t)(k0 + tk * 16 + c) * DK_ + g * 8];
            bf16x8 a0 = *reinterpret_cast<const bf16x8*>(Kb);
            bf16x8 a1 = *reinterpret_cast<const bf16x8*>(Kb + 32);
            acc[tk] = __builtin_amdgcn_mfma_f32_16x16x32_bf16(a0, qf0, acc[tk], 0, 0, 0);
            acc[tk] = __builtin_amdgcn_mfma_f32_16x16x32_bf16(a1, qf1, acc[tk], 0, 0, 0);
        }
#pragma unroll
        for (int tk = 0; tk < 4; ++tk) {
            f32x4 pv;
            bf16x4 pb;
#pragma unroll
            for (int r = 0; r < 4; ++r) {
                float p = __expf(acc[tk][r] * 0.125f) * inv_l;
                p = ((word >> (tk * 16 + g * 4 + r)) & 1) ? p : 0.f;
                pv[r] = p;
                pb[r] = (bf16_t)p;
            }
            *reinterpret_cast<f32x4*>(&A[k0 + tk * 16 + g * 4]) = pv;
            *reinterpret_cast<bf16x4*>(&Ps[w][c][tk * 16 + g * 4]) = pb;
        }
        // wave-private LDS write -> read; no barrier, just drain DS queue
        asm volatile("s_waitcnt lgkmcnt(0)" ::: "memory");
        bf16x8 pa0 = *reinterpret_cast<const bf16x8*>(&Ps[w][c][g * 8]);
        bf16x8 pa1 = *reinterpret_cast<const bf16x8*>(&Ps[w][c][32 + g * 8]);
#pragma unroll
        for (int tk = 0; tk < 4; ++tk) {
            const bf16_t* Vb = &V[(size_t)(tk * 16 + c) * S_ + k0 + g * 8];
            bf16x8 b0 = *reinterpret_cast<const bf16x8*>(Vb);
            bf16x8 b1 = *reinterpret_cast<const bf16x8*>(Vb + 32);
            oacc[tk] = __builtin_amdgcn_mfma_f32_16x16x32_bf16(pa0, b0, oacc[tk], 0, 0, 0);
            oacc[tk] = __builtin_amdgcn_mfma_f32_16x16x32_bf16(pa1, b1, oacc[tk], 0, 0, 0);
        }
    }

    // ---- pair-reduce oacc across key halves, then ctx write by half 0 ----
    if (half == 1) {
#pragma unroll
        for (int j = 0; j < 16; ++j) Ored[sub][j][l] = oacc[j >> 2][j & 3];
    }
    __syncthreads();
    if (half == 0) {
#pragma unroll
        for (int j = 0; j < 16; ++j) oacc[j >> 2][j & 3] += Ored[sub][j][l];
        // ctx write: row = q0 + g*4 + r, col = h*64 + tk*16 + c
#pragma unroll
        for (int tk = 0; tk < 4; ++tk) {
#pragma unroll
            for (int r = 0; r < 4; ++r) {
                int q = q0 + g * 4 + r;
                ctx[((size_t)b * S_ + q) * D_ + h * DK_ + tk * 16 + c] = (bf16_t)oacc[tk][r];
            }
        }
    }
}

// ---------------------------------------------------------------------------
// Output projection + bias + residual -> x (fp32). A = ctx bf16, B = Wo fp32.
// ---------------------------------------------------------------------------
__global__ __launch_bounds__(256) void oproj_mfma(const bf16_t* __restrict__ ctx,
        const float* __restrict__ Wo, const float* __restrict__ bo,
        const float* __restrict__ resid, float* __restrict__ x)
{
    __shared__ bf16_t As[64][72];
    __shared__ bf16_t Bs[64][72];
    int tid = threadIdx.x;
    int w = tid >> 6, l = tid & 63;
    int m0 = blockIdx.y * 64, n0 = blockIdx.x * 64;
    f32x4 acc[4] = {};
    for (int k0 = 0; k0 < D_; k0 += 64) {
#pragma unroll
        for (int i = 0; i < 2; ++i) {
            int u = tid + i * 256;
            int r = u >> 3, c8 = (u & 7) * 8;
            *reinterpret_cast<bf16x8*>(&As[r][c8]) =
                *reinterpret_cast<const bf16x8*>(&ctx[(size_t)(m0 + r) * D_ + k0 + c8]);
        }
#pragma unroll
        for (int i = 0; i < 4; ++i) {
            int u = tid + i * 256;
            int r = u >> 4, c4 = (u & 15) * 4;
            float4 wv = *reinterpret_cast<const float4*>(&Wo[(size_t)(n0 + r) * D_ + k0 + c4]);
            bf16x4 bw = { (bf16_t)wv.x, (bf16_t)wv.y, (bf16_t)wv.z, (bf16_t)wv.w };
            *reinterpret_cast<bf16x4*>(&Bs[r][c4]) = bw;
        }
        __syncthreads();
#pragma unroll
        for (int kk = 0; kk < 64; kk += 32) {
            bf16x8 a = *reinterpret_cast<const bf16x8*>(&As[w * 16 + (l & 15)][kk + (l >> 4) * 8]);
#pragma unroll
            for (int t = 0; t < 4; ++t) {
                bf16x8 b = *reinterpret_cast<const bf16x8*>(&Bs[t * 16 + (l & 15)][kk + (l >> 4) * 8]);
                acc[t] = __builtin_amdgcn_mfma_f32_16x16x32_bf16(a, b, acc[t], 0, 0, 0);
            }
        }
        __syncthreads();
    }
#pragma unroll
    for (int t = 0; t < 4; ++t) {
#pragma unroll
        for (int r = 0; r < 4; ++r) {
            int m = m0 + w * 16 + (l >> 4) * 4 + r;
            int n = n0 + t * 16 + (l & 15);
            x[(size_t)m * D_ + n] = acc[t][r] + bo[n] + resid[(size_t)m * D_ + n];
        }
    }
}

// ---------------------------------------------------------------------------
// LayerNorm over last dim (1024), 4096 rows
// ---------------------------------------------------------------------------
__global__ void ln_kernel(const float* __restrict__ x, const float* __restrict__ gamma,
                          const float* __restrict__ beta, float* __restrict__ out)
{
    int row = blockIdx.x;
    const float* xr = x + (size_t)row * D_;
    int tid = threadIdx.x;
    float v[4];
    float s = 0.f;
#pragma unroll
    for (int i = 0; i < 4; ++i) {
        v[i] = xr[tid + i * 256];
        s += v[i];
    }
#pragma unroll
    for (int off = 32; off > 0; off >>= 1) s += __shfl_xor(s, off);
    __shared__ float red[4];
    int wid = tid >> 6, lane = tid & 63;
    if (lane == 0) red[wid] = s;
    __syncthreads();
    float mu = (red[0] + red[1] + red[2] + red[3]) * (1.0f / D_);
    float vs = 0.f;
#pragma unroll
    for (int i = 0; i < 4; ++i) {
        float d = v[i] - mu;
        vs += d * d;
    }
#pragma unroll
    for (int off = 32; off > 0; off >>= 1) vs += __shfl_xor(vs, off);
    __syncthreads();
    __shared__ float red2[4];
    if (lane == 0) red2[wid] = vs;
    __syncthreads();
    float var = (red2[0] + red2[1] + red2[2] + red2[3]) * (1.0f / D_);
    float rs = rsqrtf(var + EPS_);
#pragma unroll
    for (int i = 0; i < 4; ++i) {
        int c = tid + i * 256;
        out[(size_t)row * D_ + c] = (v[i] - mu) * rs * gamma[c] + beta[c];
    }
}

extern "C" void kernel_launch(void* const* d_in, const int* in_sizes, int n_in,
                              void* d_out, int out_size, void* d_ws, size_t ws_size,
                              hipStream_t stream) {
    const float* q    = (const float*)d_in[0];
    const float* k    = (const float*)d_in[1];
    const float* v    = (const float*)d_in[2];
    const int*   mask = (const int*)d_in[3];
    const float* Wq   = (const float*)d_in[4];
    const float* bq   = (const float*)d_in[5];
    const float* Wk   = (const float*)d_in[6];
    const float* bk   = (const float*)d_in[7];
    const float* Wv   = (const float*)d_in[8];
    const float* bv   = (const float*)d_in[9];
    const float* Wo   = (const float*)d_in[10];
    const float* bo   = (const float*)d_in[11];
    const float* gamma= (const float*)d_in[12];
    const float* beta = (const float*)d_in[13];

    float* out  = (float*)d_out;                       // [B,S,D]
    float* attn = out + (size_t)B_ * S_ * D_;          // [B,H,S,S]

    uint8_t* ws = (uint8_t*)d_ws;
    bf16_t* qh   = (bf16_t*)(ws);                      // 8 MB  [B,H,S,DK]
    bf16_t* kh   = (bf16_t*)(ws + ((size_t)8  << 20)); // 8 MB  [B,H,S,DK]
    bf16_t* vt   = (bf16_t*)(ws + ((size_t)16 << 20)); // 8 MB  [B,H,DK,S]
    bf16_t* ctx  = (bf16_t*)(ws + ((size_t)24 << 20)); // 8 MB  [B,S,D]
    u64*    bits = (u64*)(ws + ((size_t)32 << 20));    // 1 MB  [B,S,S/64]
    float*  x    = (float*)(ws);                       // 16 MB, aliases qh+kh (dead by then)

    dim3 blk(256);
    // B_*S_*S_ = 8,388,608 ints; 256 threads/block -> 32768 blocks exactly.
    mask_pack<<<dim3((B_ * S_ * S_) / 256), blk, 0, stream>>>(mask, bits);

    dim3 gproj(D_ / 64, (B_ * S_) / 64);               // (16, 64)
    proj_mfma<<<gproj, blk, 0, stream>>>(q, Wq, bq, qh, 0);
    proj_mfma<<<gproj, blk, 0, stream>>>(k, Wk, bk, kh, 0);
    proj_mfma<<<gproj, blk, 0, stream>>>(v, Wv, bv, vt, 1);

    // 1024 blocks x 512 threads; XCD swizzle inside the kernel.
    fused_attn<<<dim3(1024), dim3(512), 0, stream>>>(qh, kh, vt, bits, attn, ctx);

    oproj_mfma<<<gproj, blk, 0, stream>>>(ctx, Wo, bo, q, x);
    ln_kernel<<<dim3(B_ * S_), blk, 0, stream>>>(x, gamma, beta, out);
}

// Round 8
// 477.182 us; speedup vs baseline: 2.2960x; 1.4490x over previous
//
#include <hip/hip_runtime.h>
#include <math.h>

#define B_ 2
#define S_ 2048
#define D_ 1024
#define H_ 16
#define DK_ 64
#define EPS_ 1e-5f

typedef __bf16 bf16_t;
typedef __bf16 bf16x4 __attribute__((ext_vector_type(4)));
typedef __bf16 bf16x8 __attribute__((ext_vector_type(8)));
typedef float f32x4 __attribute__((ext_vector_type(4)));
typedef unsigned long long u64;

#define MFMA16(a, b, c) __builtin_amdgcn_mfma_f32_16x16x32_bf16(a, b, c, 0, 0, 0)

// ---------------------------------------------------------------------------
// Pack int32 mask [B,S,S] -> bitmask [B,S,S/64] (1 bit per entry).
// ---------------------------------------------------------------------------
__global__ __launch_bounds__(256) void mask_pack(const int* __restrict__ mask,
                                                 u64* __restrict__ bits)
{
    size_t i = (size_t)blockIdx.x * 256 + threadIdx.x;
    int m = mask[i];
    u64 b = __ballot(m != 0);
    if ((threadIdx.x & 63) == 0) bits[i >> 6] = b;
}

// ---------------------------------------------------------------------------
// Projection: Y = X @ W^T + b  (X:[4096,1024] fp32, W:[1024,1024] fp32)
// Output bf16, head-split. vmode==0 -> [B,H,S,DK]; vmode==1 -> [B,H,DK,S].
// ---------------------------------------------------------------------------
__global__ __launch_bounds__(256) void proj_mfma(const float* __restrict__ X,
        const float* __restrict__ W, const float* __restrict__ bias,
        bf16_t* __restrict__ out, int vmode)
{
    __shared__ bf16_t As[64][72];
    __shared__ bf16_t Bs[64][72];
    int tid = threadIdx.x;
    int w = tid >> 6, l = tid & 63;
    int m0 = blockIdx.y * 64, n0 = blockIdx.x * 64;
    f32x4 acc[4] = {};
    for (int k0 = 0; k0 < D_; k0 += 64) {
#pragma unroll
        for (int i = 0; i < 4; ++i) {
            int u = tid + i * 256;              // 1024 float4 units
            int r = u >> 4, c4 = (u & 15) * 4;
            float4 xv = *reinterpret_cast<const float4*>(&X[(size_t)(m0 + r) * D_ + k0 + c4]);
            bf16x4 bx = { (bf16_t)xv.x, (bf16_t)xv.y, (bf16_t)xv.z, (bf16_t)xv.w };
            *reinterpret_cast<bf16x4*>(&As[r][c4]) = bx;
            float4 wv = *reinterpret_cast<const float4*>(&W[(size_t)(n0 + r) * D_ + k0 + c4]);
            bf16x4 bw = { (bf16_t)wv.x, (bf16_t)wv.y, (bf16_t)wv.z, (bf16_t)wv.w };
            *reinterpret_cast<bf16x4*>(&Bs[r][c4]) = bw;
        }
        __syncthreads();
#pragma unroll
        for (int kk = 0; kk < 64; kk += 32) {
            bf16x8 a = *reinterpret_cast<const bf16x8*>(&As[w * 16 + (l & 15)][kk + (l >> 4) * 8]);
#pragma unroll
            for (int t = 0; t < 4; ++t) {
                bf16x8 b = *reinterpret_cast<const bf16x8*>(&Bs[t * 16 + (l & 15)][kk + (l >> 4) * 8]);
                acc[t] = MFMA16(a, b, acc[t]);
            }
        }
        __syncthreads();
    }
    int h = n0 >> 6;  // each 64-wide n-tile is exactly one head
#pragma unroll
    for (int t = 0; t < 4; ++t) {
#pragma unroll
        for (int r = 0; r < 4; ++r) {
            int m = m0 + w * 16 + (l >> 4) * 4 + r;
            int n = n0 + t * 16 + (l & 15);
            float val = acc[t][r] + bias[n];
            int b = m >> 11, s = m & (S_ - 1);
            int dk = n & 63;
            size_t idx;
            if (vmode == 0) idx = (((size_t)b * H_ + h) * S_ + s) * DK_ + dk;
            else            idx = (((size_t)b * H_ + h) * DK_ + dk) * S_ + s;
            out[idx] = (bf16_t)val;
        }
    }
}

// ---------------------------------------------------------------------------
// Fused attention, no-max softmax, LDS-staged K/V (T2 XOR swizzle, T14
// async reg-staging 2 tiles deep, one barrier per tile).
// Block = 512 thr (8 waves), 128 q-rows, all 2048 keys. Wave w owns q rows
// [q0b + w*16, +16): full row sums, no cross-wave reductions.
// Pass 1: QK^T from K_lds -> row sums of exp. Pass 2: recompute QK^T,
// p = exp*inv_l (mask bit-select), f32x4 store, Ps wave-private LDS round,
// PV MFMA from V_lds. Grid 512 blocks, XCD-swizzled (4 bh per XCD).
// ---------------------------------------------------------------------------
__global__ __launch_bounds__(512) void fused_attn(
        const bf16_t* __restrict__ qh,   // [B,H,S,DK]
        const bf16_t* __restrict__ kh,   // [B,H,S,DK]
        const bf16_t* __restrict__ vt,   // [B,H,DK,S]
        const u64*    __restrict__ bits, // [B,S,S/64]
        float* __restrict__ attn,        // [B,H,S,S]
        bf16_t* __restrict__ ctx)        // [B,S,D] bf16
{
    constexpr int TILE = 64;
    constexpr int NT = S_ / TILE;        // 32
    __shared__ bf16_t Kbuf[2][TILE * DK_];   // 2 x 8 KB
    __shared__ bf16_t Vbuf[2][TILE * DK_];   // 2 x 8 KB
    __shared__ bf16_t Ps[8][16][72];         // 18 KB wave-private P staging

    const int tid = threadIdx.x;
    const int w = tid >> 6, l = tid & 63;
    const int c = l & 15, g = l >> 4;

    // XCD swizzle: 512 blocks, hw XCD = id&7; 64 ids per XCD = 4 bh x 16 qt
    const int id = blockIdx.x;
    const int xcd = id & 7, ixd = id >> 3;
    const int bh = xcd * 4 + (ixd >> 4);
    const int qt = ixd & 15;
    const int q0 = qt * 128 + w * 16;    // wave's q base
    const int b = bh >> 4, h = bh & 15;

    const bf16_t* Q = qh + ((size_t)bh * S_ + q0) * DK_;
    const bf16_t* K = kh + (size_t)bh * S_ * DK_;
    const bf16_t* V = vt + (size_t)bh * DK_ * S_;
    const u64* Mb = bits + ((size_t)b * S_ + q0 + c) * (S_ / 64);
    float* A = attn + ((size_t)bh * S_ + q0 + c) * S_;   // lane's q row

    // Q fragment (B-operand), resident both passes
    bf16x8 qf0 = *reinterpret_cast<const bf16x8*>(&Q[c * DK_ + g * 8]);
    bf16x8 qf1 = *reinterpret_cast<const bf16x8*>(&Q[c * DK_ + 32 + g * 8]);

    // staging: 512 thr x 16 B = one 8 KB tile per instruction.
    // LDS write swizzle (T2): byte = linear ^ ((row&7)<<4); read side XORs
    // the same mask -> round-trips. Global reads stay linear/coalesced.
    const int srow = tid >> 3;           // tile row this thread stages
    const uint32_t swz = ((uint32_t)tid * 16u) ^ (uint32_t)((srow & 7) << 4);
    const uint32_t rm = (uint32_t)((c & 7) << 4);   // read-side XOR mask

    //================= pass 1: row sums of exp =================
    int cur = 0;
    bf16x8 kreg = *reinterpret_cast<const bf16x8*>(K + tid * 8);
    *reinterpret_cast<bf16x8*>((char*)&Kbuf[0][0] + swz) = kreg;
    kreg = *reinterpret_cast<const bf16x8*>(K + (size_t)TILE * DK_ + tid * 8);
    __syncthreads();

    float l_r = 0.f;
    for (int t = 0; t < NT; ++t) {
        if (t + 1 < NT) {
            *reinterpret_cast<bf16x8*>((char*)&Kbuf[cur ^ 1][0] + swz) = kreg;
            if (t + 2 < NT)
                kreg = *reinterpret_cast<const bf16x8*>(K + (size_t)(t + 2) * TILE * DK_ + tid * 8);
        }
        u64 word = Mb[t];
        const char* kb = (const char*)&Kbuf[cur][0];
        f32x4 acc[4] = {};
#pragma unroll
        for (int tk = 0; tk < 4; ++tk) {
            uint32_t base = (uint32_t)((tk * 16 + c) * 128 + g * 16);
            bf16x8 a0 = *reinterpret_cast<const bf16x8*>(kb + (base ^ rm));
            bf16x8 a1 = *reinterpret_cast<const bf16x8*>(kb + ((base + 64) ^ rm));
            acc[tk] = MFMA16(a0, qf0, acc[tk]);
            acc[tk] = MFMA16(a1, qf1, acc[tk]);
        }
        float ps = 0.f;
#pragma unroll
        for (int tk = 0; tk < 4; ++tk) {
#pragma unroll
            for (int r = 0; r < 4; ++r) {
                float e = __expf(acc[tk][r] * 0.125f);
                e = ((word >> (tk * 16 + g * 4 + r)) & 1) ? e : 0.f;
                ps += e;
            }
        }
        l_r += ps;
        __syncthreads();
        cur ^= 1;
    }
    l_r += __shfl_xor(l_r, 16);
    l_r += __shfl_xor(l_r, 32);
    const float inv_l = 1.0f / l_r;

    //================= pass 2: emit P + PV =================
    cur = 0;
    kreg = *reinterpret_cast<const bf16x8*>(K + tid * 8);
    bf16x8 vreg = *reinterpret_cast<const bf16x8*>(V + (size_t)srow * S_ + (tid & 7) * 8);
    *reinterpret_cast<bf16x8*>((char*)&Kbuf[0][0] + swz) = kreg;
    *reinterpret_cast<bf16x8*>((char*)&Vbuf[0][0] + swz) = vreg;
    kreg = *reinterpret_cast<const bf16x8*>(K + (size_t)TILE * DK_ + tid * 8);
    vreg = *reinterpret_cast<const bf16x8*>(V + (size_t)srow * S_ + TILE + (tid & 7) * 8);
    __syncthreads();

    f32x4 oacc[4] = {};
    for (int t = 0; t < NT; ++t) {
        if (t + 1 < NT) {
            *reinterpret_cast<bf16x8*>((char*)&Kbuf[cur ^ 1][0] + swz) = kreg;
            *reinterpret_cast<bf16x8*>((char*)&Vbuf[cur ^ 1][0] + swz) = vreg;
            if (t + 2 < NT) {
                kreg = *reinterpret_cast<const bf16x8*>(K + (size_t)(t + 2) * TILE * DK_ + tid * 8);
                vreg = *reinterpret_cast<const bf16x8*>(V + (size_t)srow * S_ + (t + 2) * TILE + (tid & 7) * 8);
            }
        }
        u64 word = Mb[t];
        const char* kb = (const char*)&Kbuf[cur][0];
        const char* vb = (const char*)&Vbuf[cur][0];
        f32x4 acc[4] = {};
#pragma unroll
        for (int tk = 0; tk < 4; ++tk) {
            uint32_t base = (uint32_t)((tk * 16 + c) * 128 + g * 16);
            bf16x8 a0 = *reinterpret_cast<const bf16x8*>(kb + (base ^ rm));
            bf16x8 a1 = *reinterpret_cast<const bf16x8*>(kb + ((base + 64) ^ rm));
            acc[tk] = MFMA16(a0, qf0, acc[tk]);
            acc[tk] = MFMA16(a1, qf1, acc[tk]);
        }
#pragma unroll
        for (int tk = 0; tk < 4; ++tk) {
            f32x4 pv;
            bf16x4 pb;
#pragma unroll
            for (int r = 0; r < 4; ++r) {
                float p = __expf(acc[tk][r] * 0.125f) * inv_l;
                p = ((word >> (tk * 16 + g * 4 + r)) & 1) ? p : 0.f;
                pv[r] = p;
                pb[r] = (bf16_t)p;
            }
            *reinterpret_cast<f32x4*>(&A[t * TILE + tk * 16 + g * 4]) = pv;
            *reinterpret_cast<bf16x4*>(&Ps[w][c][tk * 16 + g * 4]) = pb;
        }
        // wave-private LDS round-trip; drain DS queue, no barrier
        asm volatile("s_waitcnt lgkmcnt(0)" ::: "memory");
        bf16x8 pa0 = *reinterpret_cast<const bf16x8*>(&Ps[w][c][g * 8]);
        bf16x8 pa1 = *reinterpret_cast<const bf16x8*>(&Ps[w][c][32 + g * 8]);
#pragma unroll
        for (int tk = 0; tk < 4; ++tk) {
            uint32_t base = (uint32_t)((tk * 16 + c) * 128 + g * 16);
            bf16x8 b0 = *reinterpret_cast<const bf16x8*>(vb + (base ^ rm));
            bf16x8 b1 = *reinterpret_cast<const bf16x8*>(vb + ((base + 64) ^ rm));
            oacc[tk] = MFMA16(pa0, b0, oacc[tk]);
            oacc[tk] = MFMA16(pa1, b1, oacc[tk]);
        }
        __syncthreads();
        cur ^= 1;
    }

    // ctx write: row = q0 + g*4 + r, col = h*64 + tk*16 + c
#pragma unroll
    for (int tk = 0; tk < 4; ++tk) {
#pragma unroll
        for (int r = 0; r < 4; ++r) {
            int q = q0 + g * 4 + r;
            ctx[((size_t)b * S_ + q) * D_ + h * DK_ + tk * 16 + c] = (bf16_t)oacc[tk][r];
        }
    }
}

// ---------------------------------------------------------------------------
// Output projection + bias + residual -> x (fp32). A = ctx bf16, B = Wo fp32.
// ---------------------------------------------------------------------------
__global__ __launch_bounds__(256) void oproj_mfma(const bf16_t* __restrict__ ctx,
        const float* __restrict__ Wo, const float* __restrict__ bo,
        const float* __restrict__ resid, float* __restrict__ x)
{
    __shared__ bf16_t As[64][72];
    __shared__ bf16_t Bs[64][72];
    int tid = threadIdx.x;
    int w = tid >> 6, l = tid & 63;
    int m0 = blockIdx.y * 64, n0 = blockIdx.x * 64;
    f32x4 acc[4] = {};
    for (int k0 = 0; k0 < D_; k0 += 64) {
#pragma unroll
        for (int i = 0; i < 2; ++i) {
            int u = tid + i * 256;
            int r = u >> 3, c8 = (u & 7) * 8;
            *reinterpret_cast<bf16x8*>(&As[r][c8]) =
                *reinterpret_cast<const bf16x8*>(&ctx[(size_t)(m0 + r) * D_ + k0 + c8]);
        }
#pragma unroll
        for (int i = 0; i < 4; ++i) {
            int u = tid + i * 256;
            int r = u >> 4, c4 = (u & 15) * 4;
            float4 wv = *reinterpret_cast<const float4*>(&Wo[(size_t)(n0 + r) * D_ + k0 + c4]);
            bf16x4 bw = { (bf16_t)wv.x, (bf16_t)wv.y, (bf16_t)wv.z, (bf16_t)wv.w };
            *reinterpret_cast<bf16x4*>(&Bs[r][c4]) = bw;
        }
        __syncthreads();
#pragma unroll
        for (int kk = 0; kk < 64; kk += 32) {
            bf16x8 a = *reinterpret_cast<const bf16x8*>(&As[w * 16 + (l & 15)][kk + (l >> 4) * 8]);
#pragma unroll
            for (int t = 0; t < 4; ++t) {
                bf16x8 b = *reinterpret_cast<const bf16x8*>(&Bs[t * 16 + (l & 15)][kk + (l >> 4) * 8]);
                acc[t] = MFMA16(a, b, acc[t]);
            }
        }
        __syncthreads();
    }
#pragma unroll
    for (int t = 0; t < 4; ++t) {
#pragma unroll
        for (int r = 0; r < 4; ++r) {
            int m = m0 + w * 16 + (l >> 4) * 4 + r;
            int n = n0 + t * 16 + (l & 15);
            x[(size_t)m * D_ + n] = acc[t][r] + bo[n] + resid[(size_t)m * D_ + n];
        }
    }
}

// ---------------------------------------------------------------------------
// LayerNorm over last dim (1024), 4096 rows
// ---------------------------------------------------------------------------
__global__ void ln_kernel(const float* __restrict__ x, const float* __restrict__ gamma,
                          const float* __restrict__ beta, float* __restrict__ out)
{
    int row = blockIdx.x;
    const float* xr = x + (size_t)row * D_;
    int tid = threadIdx.x;
    float v[4];
    float s = 0.f;
#pragma unroll
    for (int i = 0; i < 4; ++i) {
        v[i] = xr[tid + i * 256];
        s += v[i];
    }
#pragma unroll
    for (int off = 32; off > 0; off >>= 1) s += __shfl_xor(s, off);
    __shared__ float red[4];
    int wid = tid >> 6, lane = tid & 63;
    if (lane == 0) red[wid] = s;
    __syncthreads();
    float mu = (red[0] + red[1] + red[2] + red[3]) * (1.0f / D_);
    float vs = 0.f;
#pragma unroll
    for (int i = 0; i < 4; ++i) {
        float d = v[i] - mu;
        vs += d * d;
    }
#pragma unroll
    for (int off = 32; off > 0; off >>= 1) vs += __shfl_xor(vs, off);
    __syncthreads();
    __shared__ float red2[4];
    if (lane == 0) red2[wid] = vs;
    __syncthreads();
    float var = (red2[0] + red2[1] + red2[2] + red2[3]) * (1.0f / D_);
    float rs = rsqrtf(var + EPS_);
#pragma unroll
    for (int i = 0; i < 4; ++i) {
        int c = tid + i * 256;
        out[(size_t)row * D_ + c] = (v[i] - mu) * rs * gamma[c] + beta[c];
    }
}

extern "C" void kernel_launch(void* const* d_in, const int* in_sizes, int n_in,
                              void* d_out, int out_size, void* d_ws, size_t ws_size,
                              hipStream_t stream) {
    const float* q    = (const float*)d_in[0];
    const float* k    = (const float*)d_in[1];
    const float* v    = (const float*)d_in[2];
    const int*   mask = (const int*)d_in[3];
    const float* Wq   = (const float*)d_in[4];
    const float* bq   = (const float*)d_in[5];
    const float* Wk   = (const float*)d_in[6];
    const float* bk   = (const float*)d_in[7];
    const float* Wv   = (const float*)d_in[8];
    const float* bv   = (const float*)d_in[9];
    const float* Wo   = (const float*)d_in[10];
    const float* bo   = (const float*)d_in[11];
    const float* gamma= (const float*)d_in[12];
    const float* beta = (const float*)d_in[13];

    float* out  = (float*)d_out;                       // [B,S,D]
    float* attn = out + (size_t)B_ * S_ * D_;          // [B,H,S,S]

    uint8_t* ws = (uint8_t*)d_ws;
    bf16_t* qh   = (bf16_t*)(ws);                      // 8 MB  [B,H,S,DK]
    bf16_t* kh   = (bf16_t*)(ws + ((size_t)8  << 20)); // 8 MB  [B,H,S,DK]
    bf16_t* vt   = (bf16_t*)(ws + ((size_t)16 << 20)); // 8 MB  [B,H,DK,S]
    bf16_t* ctx  = (bf16_t*)(ws + ((size_t)24 << 20)); // 8 MB  [B,S,D]
    u64*    bits = (u64*)(ws + ((size_t)32 << 20));    // 1 MB  [B,S,S/64]
    float*  x    = (float*)(ws);                       // 16 MB, aliases qh+kh (dead by then)

    dim3 blk(256);
    // B_*S_*S_ = 8,388,608 ints; 256 threads/block -> 32768 blocks exactly.
    mask_pack<<<dim3((B_ * S_ * S_) / 256), blk, 0, stream>>>(mask, bits);

    dim3 gproj(D_ / 64, (B_ * S_) / 64);               // (16, 64)
    proj_mfma<<<gproj, blk, 0, stream>>>(q, Wq, bq, qh, 0);
    proj_mfma<<<gproj, blk, 0, stream>>>(k, Wk, bk, kh, 0);
    proj_mfma<<<gproj, blk, 0, stream>>>(v, Wv, bv, vt, 1);

    // 512 blocks x 512 threads; XCD swizzle inside the kernel.
    fused_attn<<<dim3(512), dim3(512), 0, stream>>>(qh, kh, vt, bits, attn, ctx);

    oproj_mfma<<<gproj, blk, 0, stream>>>(ctx, Wo, bo, q, x);
    ln_kernel<<<dim3(B_ * S_), blk, 0, stream>>>(x, gamma, beta, out);
}

// Round 9
// 373.795 us; speedup vs baseline: 2.9311x; 1.2766x over previous
//
#include <hip/hip_runtime.h>
#include <math.h>

#define B_ 2
#define S_ 2048
#define D_ 1024
#define H_ 16
#define DK_ 64
#define EPS_ 1e-5f

typedef __bf16 bf16_t;
typedef __bf16 bf16x4 __attribute__((ext_vector_type(4)));
typedef __bf16 bf16x8 __attribute__((ext_vector_type(8)));
typedef float f32x4 __attribute__((ext_vector_type(4)));
typedef unsigned long long u64;

#define MFMA16(a, b, c) __builtin_amdgcn_mfma_f32_16x16x32_bf16(a, b, c, 0, 0, 0)

// ---------------------------------------------------------------------------
// fp32 -> bf16 converters (8 elems/thread).
// ---------------------------------------------------------------------------
__global__ __launch_bounds__(256) void cvt3(const float* __restrict__ a,
        const float* __restrict__ b, const float* __restrict__ c,
        bf16_t* __restrict__ oa, bf16_t* __restrict__ ob, bf16_t* __restrict__ oc)
{
    int region = blockIdx.x >> 11;               // 2048 blocks per tensor
    int i = ((blockIdx.x & 2047) << 8) + threadIdx.x;   // vec8 index
    const float* in = (region == 0) ? a : (region == 1) ? b : c;
    bf16_t* out = (region == 0) ? oa : (region == 1) ? ob : oc;
    float4 v0 = reinterpret_cast<const float4*>(in)[i * 2];
    float4 v1 = reinterpret_cast<const float4*>(in)[i * 2 + 1];
    bf16x8 o = { (bf16_t)v0.x, (bf16_t)v0.y, (bf16_t)v0.z, (bf16_t)v0.w,
                 (bf16_t)v1.x, (bf16_t)v1.y, (bf16_t)v1.z, (bf16_t)v1.w };
    reinterpret_cast<bf16x8*>(out)[i] = o;
}

__global__ __launch_bounds__(256) void cvt4(const float* __restrict__ a,
        const float* __restrict__ b, const float* __restrict__ c, const float* __restrict__ d,
        bf16_t* __restrict__ oa, bf16_t* __restrict__ ob, bf16_t* __restrict__ oc,
        bf16_t* __restrict__ od)
{
    int region = blockIdx.x >> 9;                // 512 blocks per tensor
    int i = ((blockIdx.x & 511) << 8) + threadIdx.x;
    const float* in = (region == 0) ? a : (region == 1) ? b : (region == 2) ? c : d;
    bf16_t* out = (region == 0) ? oa : (region == 1) ? ob : (region == 2) ? oc : od;
    float4 v0 = reinterpret_cast<const float4*>(in)[i * 2];
    float4 v1 = reinterpret_cast<const float4*>(in)[i * 2 + 1];
    bf16x8 o = { (bf16_t)v0.x, (bf16_t)v0.y, (bf16_t)v0.z, (bf16_t)v0.w,
                 (bf16_t)v1.x, (bf16_t)v1.y, (bf16_t)v1.z, (bf16_t)v1.w };
    reinterpret_cast<bf16x8*>(out)[i] = o;
}

// ---------------------------------------------------------------------------
// Pack int32 mask [B,S,S] -> bitmask [B,S,S/64] (1 bit per entry).
// ---------------------------------------------------------------------------
__global__ __launch_bounds__(256) void mask_pack(const int* __restrict__ mask,
                                                 u64* __restrict__ bits)
{
    size_t i = (size_t)blockIdx.x * 256 + threadIdx.x;
    int m = mask[i];
    u64 b = __ballot(m != 0);
    if ((threadIdx.x & 63) == 0) bits[i >> 6] = b;
}

// ---------------------------------------------------------------------------
// 128x128-tile bf16 GEMM: Y = X @ W^T + bias. 256 thr / 4 waves (2x2 of 64x64).
// K = 1024, BK = 64, single-buffer LDS w/ T2 XOR swizzle + T14 reg prefetch.
// mode 0: out bf16 head-split [B,H,S,DK]
// mode 1: out bf16 transposed [B,H,DK,S]  (X staged into B-slot, W into A-slot)
// mode 2: out fp32 [M,D] = acc + bias + resid (residual add)
// ---------------------------------------------------------------------------
__global__ __launch_bounds__(256) void gemm_bf16(
        const bf16_t* __restrict__ X,   // [4096,1024]
        const bf16_t* __restrict__ W,   // [1024,1024] rows = n
        const float*  __restrict__ bias,
        const float*  __restrict__ resid,
        float* __restrict__ xout,
        bf16_t* __restrict__ bout,
        int mode)
{
    __shared__ bf16_t As[128 * 64];
    __shared__ bf16_t Bs[128 * 64];
    const int tid = threadIdx.x;
    const int w = tid >> 6, l = tid & 63;
    const int c = l & 15, g = l >> 4;
    const int wr = w >> 1, wc = w & 1;
    const int m0 = blockIdx.y * 128, n0 = blockIdx.x * 128;

    const bf16_t* Asrc = (mode == 1) ? (W + (size_t)n0 * D_) : (X + (size_t)m0 * D_);
    const bf16_t* Bsrc = (mode == 1) ? (X + (size_t)m0 * D_) : (W + (size_t)n0 * D_);

    // staging geometry: 1024 slots of 16B per tile; thread owns slots tid+i*256
    int srow[4], scol[4];
    uint32_t soff[4];
#pragma unroll
    for (int i = 0; i < 4; ++i) {
        int s = tid + i * 256;
        srow[i] = s >> 3;                 // tile row 0..127
        scol[i] = s & 7;                  // 16B col slot 0..7
        soff[i] = (uint32_t)(s * 16) ^ (uint32_t)((srow[i] & 7) << 4);  // swizzled LDS byte
    }

    bf16x8 areg[4], breg[4];
#pragma unroll
    for (int i = 0; i < 4; ++i) {
        areg[i] = *reinterpret_cast<const bf16x8*>(Asrc + (size_t)srow[i] * D_ + scol[i] * 8);
        breg[i] = *reinterpret_cast<const bf16x8*>(Bsrc + (size_t)srow[i] * D_ + scol[i] * 8);
    }

    f32x4 acc[4][4] = {};
    for (int kt = 0; kt < 16; ++kt) {
        // write staged regs for tile kt
#pragma unroll
        for (int i = 0; i < 4; ++i) {
            *reinterpret_cast<bf16x8*>((char*)As + soff[i]) = areg[i];
            *reinterpret_cast<bf16x8*>((char*)Bs + soff[i]) = breg[i];
        }
        __syncthreads();
        // issue loads for tile kt+1 (overlap with MFMA below)
        if (kt + 1 < 16) {
            int k0 = (kt + 1) * 64;
#pragma unroll
            for (int i = 0; i < 4; ++i) {
                areg[i] = *reinterpret_cast<const bf16x8*>(Asrc + (size_t)srow[i] * D_ + k0 + scol[i] * 8);
                breg[i] = *reinterpret_cast<const bf16x8*>(Bsrc + (size_t)srow[i] * D_ + k0 + scol[i] * 8);
            }
        }
        // compute
        bf16x8 bf0[4], bf1[4];
#pragma unroll
        for (int j = 0; j < 4; ++j) {
            int R = wc * 64 + j * 16 + c;
            const char* base = (const char*)Bs + R * 128;
            uint32_t msk = (uint32_t)((R & 7) << 4);
            bf0[j] = *reinterpret_cast<const bf16x8*>(base + ((g * 16) ^ msk));
            bf1[j] = *reinterpret_cast<const bf16x8*>(base + ((64 + g * 16) ^ msk));
        }
#pragma unroll
        for (int i = 0; i < 4; ++i) {
            int R = wr * 64 + i * 16 + c;
            const char* base = (const char*)As + R * 128;
            uint32_t msk = (uint32_t)((R & 7) << 4);
            bf16x8 a0 = *reinterpret_cast<const bf16x8*>(base + ((g * 16) ^ msk));
            bf16x8 a1 = *reinterpret_cast<const bf16x8*>(base + ((64 + g * 16) ^ msk));
#pragma unroll
            for (int j = 0; j < 4; ++j) {
                acc[i][j] = MFMA16(a0, bf0[j], acc[i][j]);
                acc[i][j] = MFMA16(a1, bf1[j], acc[i][j]);
            }
        }
        __syncthreads();   // all reads done before next tile's writes
    }

    // epilogue: P = A-tile row space (output rows), Qd = B-tile row space
#pragma unroll
    for (int i = 0; i < 4; ++i) {
#pragma unroll
        for (int j = 0; j < 4; ++j) {
#pragma unroll
            for (int r = 0; r < 4; ++r) {
                int P  = wr * 64 + i * 16 + g * 4 + r;
                int Qd = wc * 64 + j * 16 + c;
                float val = acc[i][j][r];
                if (mode == 2) {
                    int m = m0 + P, n = n0 + Qd;
                    xout[(size_t)m * D_ + n] = val + bias[n] + resid[(size_t)m * D_ + n];
                } else if (mode == 0) {
                    int m = m0 + P, n = n0 + Qd;
                    int bb = m >> 11, s = m & (S_ - 1);
                    int h = n >> 6, dk = n & 63;
                    bout[(((size_t)bb * H_ + h) * S_ + s) * DK_ + dk] = (bf16_t)(val + bias[n]);
                } else {
                    int n = n0 + P, m = m0 + Qd;
                    int bb = m >> 11, s = m & (S_ - 1);
                    int h = n >> 6, dk = n & 63;
                    bout[(((size_t)bb * H_ + h) * DK_ + dk) * S_ + s] = (bf16_t)(val + bias[n]);
                }
            }
        }
    }
}

// ---------------------------------------------------------------------------
// Fused attention (unchanged from r8): no-max softmax, LDS-staged K/V,
// T2 swizzle, T14 reg prefetch, 1 barrier/tile, XCD swizzle.
// ---------------------------------------------------------------------------
__global__ __launch_bounds__(512) void fused_attn(
        const bf16_t* __restrict__ qh,   // [B,H,S,DK]
        const bf16_t* __restrict__ kh,   // [B,H,S,DK]
        const bf16_t* __restrict__ vt,   // [B,H,DK,S]
        const u64*    __restrict__ bits, // [B,S,S/64]
        float* __restrict__ attn,        // [B,H,S,S]
        bf16_t* __restrict__ ctx)        // [B,S,D] bf16
{
    constexpr int TILE = 64;
    constexpr int NT = S_ / TILE;        // 32
    __shared__ bf16_t Kbuf[2][TILE * DK_];   // 2 x 8 KB
    __shared__ bf16_t Vbuf[2][TILE * DK_];   // 2 x 8 KB
    __shared__ bf16_t Ps[8][16][72];         // 18 KB wave-private P staging

    const int tid = threadIdx.x;
    const int w = tid >> 6, l = tid & 63;
    const int c = l & 15, g = l >> 4;

    const int id = blockIdx.x;
    const int xcd = id & 7, ixd = id >> 3;
    const int bh = xcd * 4 + (ixd >> 4);
    const int qt = ixd & 15;
    const int q0 = qt * 128 + w * 16;    // wave's q base
    const int b = bh >> 4, h = bh & 15;

    const bf16_t* Q = qh + ((size_t)bh * S_ + q0) * DK_;
    const bf16_t* K = kh + (size_t)bh * S_ * DK_;
    const bf16_t* V = vt + (size_t)bh * DK_ * S_;
    const u64* Mb = bits + ((size_t)b * S_ + q0 + c) * (S_ / 64);
    float* A = attn + ((size_t)bh * S_ + q0 + c) * S_;   // lane's q row

    bf16x8 qf0 = *reinterpret_cast<const bf16x8*>(&Q[c * DK_ + g * 8]);
    bf16x8 qf1 = *reinterpret_cast<const bf16x8*>(&Q[c * DK_ + 32 + g * 8]);

    const int srow = tid >> 3;
    const uint32_t swz = ((uint32_t)tid * 16u) ^ (uint32_t)((srow & 7) << 4);
    const uint32_t rm = (uint32_t)((c & 7) << 4);

    //================= pass 1: row sums of exp =================
    int cur = 0;
    bf16x8 kreg = *reinterpret_cast<const bf16x8*>(K + tid * 8);
    *reinterpret_cast<bf16x8*>((char*)&Kbuf[0][0] + swz) = kreg;
    kreg = *reinterpret_cast<const bf16x8*>(K + (size_t)TILE * DK_ + tid * 8);
    __syncthreads();

    float l_r = 0.f;
    for (int t = 0; t < NT; ++t) {
        if (t + 1 < NT) {
            *reinterpret_cast<bf16x8*>((char*)&Kbuf[cur ^ 1][0] + swz) = kreg;
            if (t + 2 < NT)
                kreg = *reinterpret_cast<const bf16x8*>(K + (size_t)(t + 2) * TILE * DK_ + tid * 8);
        }
        u64 word = Mb[t];
        const char* kb = (const char*)&Kbuf[cur][0];
        f32x4 acc[4] = {};
#pragma unroll
        for (int tk = 0; tk < 4; ++tk) {
            uint32_t base = (uint32_t)((tk * 16 + c) * 128 + g * 16);
            bf16x8 a0 = *reinterpret_cast<const bf16x8*>(kb + (base ^ rm));
            bf16x8 a1 = *reinterpret_cast<const bf16x8*>(kb + ((base + 64) ^ rm));
            acc[tk] = MFMA16(a0, qf0, acc[tk]);
            acc[tk] = MFMA16(a1, qf1, acc[tk]);
        }
        float ps = 0.f;
#pragma unroll
        for (int tk = 0; tk < 4; ++tk) {
#pragma unroll
            for (int r = 0; r < 4; ++r) {
                float e = __expf(acc[tk][r] * 0.125f);
                e = ((word >> (tk * 16 + g * 4 + r)) & 1) ? e : 0.f;
                ps += e;
            }
        }
        l_r += ps;
        __syncthreads();
        cur ^= 1;
    }
    l_r += __shfl_xor(l_r, 16);
    l_r += __shfl_xor(l_r, 32);
    const float inv_l = 1.0f / l_r;

    //================= pass 2: emit P + PV =================
    cur = 0;
    kreg = *reinterpret_cast<const bf16x8*>(K + tid * 8);
    bf16x8 vreg = *reinterpret_cast<const bf16x8*>(V + (size_t)srow * S_ + (tid & 7) * 8);
    *reinterpret_cast<bf16x8*>((char*)&Kbuf[0][0] + swz) = kreg;
    *reinterpret_cast<bf16x8*>((char*)&Vbuf[0][0] + swz) = vreg;
    kreg = *reinterpret_cast<const bf16x8*>(K + (size_t)TILE * DK_ + tid * 8);
    vreg = *reinterpret_cast<const bf16x8*>(V + (size_t)srow * S_ + TILE + (tid & 7) * 8);
    __syncthreads();

    f32x4 oacc[4] = {};
    for (int t = 0; t < NT; ++t) {
        if (t + 1 < NT) {
            *reinterpret_cast<bf16x8*>((char*)&Kbuf[cur ^ 1][0] + swz) = kreg;
            *reinterpret_cast<bf16x8*>((char*)&Vbuf[cur ^ 1][0] + swz) = vreg;
            if (t + 2 < NT) {
                kreg = *reinterpret_cast<const bf16x8*>(K + (size_t)(t + 2) * TILE * DK_ + tid * 8);
                vreg = *reinterpret_cast<const bf16x8*>(V + (size_t)srow * S_ + (t + 2) * TILE + (tid & 7) * 8);
            }
        }
        u64 word = Mb[t];
        const char* kb = (const char*)&Kbuf[cur][0];
        const char* vb = (const char*)&Vbuf[cur][0];
        f32x4 acc[4] = {};
#pragma unroll
        for (int tk = 0; tk < 4; ++tk) {
            uint32_t base = (uint32_t)((tk * 16 + c) * 128 + g * 16);
            bf16x8 a0 = *reinterpret_cast<const bf16x8*>(kb + (base ^ rm));
            bf16x8 a1 = *reinterpret_cast<const bf16x8*>(kb + ((base + 64) ^ rm));
            acc[tk] = MFMA16(a0, qf0, acc[tk]);
            acc[tk] = MFMA16(a1, qf1, acc[tk]);
        }
#pragma unroll
        for (int tk = 0; tk < 4; ++tk) {
            f32x4 pv;
            bf16x4 pb;
#pragma unroll
            for (int r = 0; r < 4; ++r) {
                float p = __expf(acc[tk][r] * 0.125f) * inv_l;
                p = ((word >> (tk * 16 + g * 4 + r)) & 1) ? p : 0.f;
                pv[r] = p;
                pb[r] = (bf16_t)p;
            }
            *reinterpret_cast<f32x4*>(&A[t * TILE + tk * 16 + g * 4]) = pv;
            *reinterpret_cast<bf16x4*>(&Ps[w][c][tk * 16 + g * 4]) = pb;
        }
        asm volatile("s_waitcnt lgkmcnt(0)" ::: "memory");
        bf16x8 pa0 = *reinterpret_cast<const bf16x8*>(&Ps[w][c][g * 8]);
        bf16x8 pa1 = *reinterpret_cast<const bf16x8*>(&Ps[w][c][32 + g * 8]);
#pragma unroll
        for (int tk = 0; tk < 4; ++tk) {
            uint32_t base = (uint32_t)((tk * 16 + c) * 128 + g * 16);
            bf16x8 b0 = *reinterpret_cast<const bf16x8*>(vb + (base ^ rm));
            bf16x8 b1 = *reinterpret_cast<const bf16x8*>(vb + ((base + 64) ^ rm));
            oacc[tk] = MFMA16(pa0, b0, oacc[tk]);
            oacc[tk] = MFMA16(pa1, b1, oacc[tk]);
        }
        __syncthreads();
        cur ^= 1;
    }

#pragma unroll
    for (int tk = 0; tk < 4; ++tk) {
#pragma unroll
        for (int r = 0; r < 4; ++r) {
            int q = q0 + g * 4 + r;
            ctx[((size_t)b * S_ + q) * D_ + h * DK_ + tk * 16 + c] = (bf16_t)oacc[tk][r];
        }
    }
}

// ---------------------------------------------------------------------------
// LayerNorm over last dim (1024), 4096 rows
// ---------------------------------------------------------------------------
__global__ void ln_kernel(const float* __restrict__ x, const float* __restrict__ gamma,
                          const float* __restrict__ beta, float* __restrict__ out)
{
    int row = blockIdx.x;
    const float* xr = x + (size_t)row * D_;
    int tid = threadIdx.x;
    float v[4];
    float s = 0.f;
#pragma unroll
    for (int i = 0; i < 4; ++i) {
        v[i] = xr[tid + i * 256];
        s += v[i];
    }
#pragma unroll
    for (int off = 32; off > 0; off >>= 1) s += __shfl_xor(s, off);
    __shared__ float red[4];
    int wid = tid >> 6, lane = tid & 63;
    if (lane == 0) red[wid] = s;
    __syncthreads();
    float mu = (red[0] + red[1] + red[2] + red[3]) * (1.0f / D_);
    float vs = 0.f;
#pragma unroll
    for (int i = 0; i < 4; ++i) {
        float d = v[i] - mu;
        vs += d * d;
    }
#pragma unroll
    for (int off = 32; off > 0; off >>= 1) vs += __shfl_xor(vs, off);
    __syncthreads();
    __shared__ float red2[4];
    if (lane == 0) red2[wid] = vs;
    __syncthreads();
    float var = (red2[0] + red2[1] + red2[2] + red2[3]) * (1.0f / D_);
    float rs = rsqrtf(var + EPS_);
#pragma unroll
    for (int i = 0; i < 4; ++i) {
        int c = tid + i * 256;
        out[(size_t)row * D_ + c] = (v[i] - mu) * rs * gamma[c] + beta[c];
    }
}

extern "C" void kernel_launch(void* const* d_in, const int* in_sizes, int n_in,
                              void* d_out, int out_size, void* d_ws, size_t ws_size,
                              hipStream_t stream) {
    const float* q    = (const float*)d_in[0];
    const float* k    = (const float*)d_in[1];
    const float* v    = (const float*)d_in[2];
    const int*   mask = (const int*)d_in[3];
    const float* Wq   = (const float*)d_in[4];
    const float* bq   = (const float*)d_in[5];
    const float* Wk   = (const float*)d_in[6];
    const float* bk   = (const float*)d_in[7];
    const float* Wv   = (const float*)d_in[8];
    const float* bv   = (const float*)d_in[9];
    const float* Wo   = (const float*)d_in[10];
    const float* bo   = (const float*)d_in[11];
    const float* gamma= (const float*)d_in[12];
    const float* beta = (const float*)d_in[13];

    float* out  = (float*)d_out;                       // [B,S,D]
    float* attn = out + (size_t)B_ * S_ * D_;          // [B,H,S,S]

    // Workspace (48 MB peak, temporal aliasing):
    //  [0,8)   xq  -> kh   (kh written after xq dead)
    //  [8,16)  xk  -> vt
    //  [16,24) xv  -> ctx
    //  [24,32) wqb,wkb,wvb,wob (2 MB each; wob live till oproj)
    //  [32,40) qh  -> x (fp32, 16 MB, spans [32,48); qh+bits dead by then)
    //  [40,41) bits
    uint8_t* ws = (uint8_t*)d_ws;
    bf16_t* xq  = (bf16_t*)(ws);
    bf16_t* xk  = (bf16_t*)(ws + ((size_t)8  << 20));
    bf16_t* xv  = (bf16_t*)(ws + ((size_t)16 << 20));
    bf16_t* wqb = (bf16_t*)(ws + ((size_t)24 << 20));
    bf16_t* wkb = (bf16_t*)(ws + ((size_t)26 << 20));
    bf16_t* wvb = (bf16_t*)(ws + ((size_t)28 << 20));
    bf16_t* wob = (bf16_t*)(ws + ((size_t)30 << 20));
    bf16_t* qh  = (bf16_t*)(ws + ((size_t)32 << 20));
    u64*    bits= (u64*)   (ws + ((size_t)40 << 20));
    bf16_t* kh  = (bf16_t*)(ws);                       // over xq
    bf16_t* vt  = (bf16_t*)(ws + ((size_t)8  << 20));  // over xk
    bf16_t* ctx = (bf16_t*)(ws + ((size_t)16 << 20));  // over xv
    float*  x   = (float*) (ws + ((size_t)32 << 20));  // over qh+bits

    dim3 blk(256);
    cvt3<<<dim3(6144), blk, 0, stream>>>(q, k, v, xq, xk, xv);
    cvt4<<<dim3(2048), blk, 0, stream>>>(Wq, Wk, Wv, Wo, wqb, wkb, wvb, wob);
    mask_pack<<<dim3((B_ * S_ * S_) / 256), blk, 0, stream>>>(mask, bits);

    dim3 ggemm(D_ / 128, (B_ * S_) / 128);             // (8, 32)
    gemm_bf16<<<ggemm, blk, 0, stream>>>(xq, wqb, bq, nullptr, nullptr, qh, 0);
    gemm_bf16<<<ggemm, blk, 0, stream>>>(xk, wkb, bk, nullptr, nullptr, kh, 0);
    gemm_bf16<<<ggemm, blk, 0, stream>>>(xv, wvb, bv, nullptr, nullptr, vt, 1);

    fused_attn<<<dim3(512), dim3(512), 0, stream>>>(qh, kh, vt, bits, attn, ctx);

    gemm_bf16<<<ggemm, blk, 0, stream>>>(ctx, wob, bo, q, x, nullptr, 2);
    ln_kernel<<<dim3(B_ * S_), blk, 0, stream>>>(x, gamma, beta, out);
}